// Round 1
// baseline (475.793 us; speedup 1.0000x reference)
//
#include <hip/hip_runtime.h>

#define B_ 64
#define N_ 256
#define V_ 2048
#define LRD 64
#define E_ 1024
#define MROWS 16384  // B_*N_

// ws layout (floats):
//   scale  [128]          @ 0
//   d      [16384]        @ 128
//   s      [16384]        @ 16512
//   LR     [16384*128]    @ 32896     (per row: [0..63]=right(U1), [64..127]=left(U2))
//   featsT [2048*64]      @ 2130048   (featsT[v*64+b])
//   xT     [1024*64]      @ 2261120   (xT[e*64+b])
#define OFF_SCALE  0
#define OFF_D      128
#define OFF_S      16512
#define OFF_LR     32896
#define OFF_FT     2130048
#define OFF_XT     2261120

// ---------------- kernel 1: weight-norm scales -------------------
__global__ void knorm(const float* __restrict__ U1v, const float* __restrict__ U1g,
                      const float* __restrict__ U2v, const float* __restrict__ U2g,
                      float* __restrict__ scale) {
    __shared__ float red[256];
    int r = blockIdx.x;  // 0..127
    const float* v = (r < 64) ? (U1v + (size_t)r * V_) : (U2v + (size_t)(r - 64) * V_);
    float ss = 0.f;
    for (int i = threadIdx.x; i < V_; i += 256) { float x = v[i]; ss += x * x; }
    red[threadIdx.x] = ss;
    __syncthreads();
    for (int o = 128; o > 0; o >>= 1) {
        if (threadIdx.x < (unsigned)o) red[threadIdx.x] += red[threadIdx.x + o];
        __syncthreads();
    }
    if (threadIdx.x == 0) {
        float g = (r < 64) ? U1g[r] : U2g[r - 64];
        scale[r] = g * rsqrtf(red[0]);
    }
}

// ---------------- kernel 2: left/right projections ----------------
// C[16384x128] = relu(Vmat[16384x2048] * W[128x2048]^T * scale + bias)
// block: 32 M-rows x 128 cols, 256 threads, 4x4 register tile, K-chunk 32.
#define KC 32
__global__ __launch_bounds__(256) void gemm_lr(
    const float* __restrict__ Vmat, const float* __restrict__ U1v, const float* __restrict__ U2v,
    const float* __restrict__ scale, const float* __restrict__ U1b, const float* __restrict__ U2b,
    float* __restrict__ LR) {
    __shared__ float As[KC][36];   // [k][m], +4 pad (16B-aligned rows)
    __shared__ float Ws[KC][132];  // [k][r], +4 pad
    const int t = threadIdx.x;
    const int m0 = blockIdx.x * 32;
    const int ng = t & 31;   // col group (4 cols each)
    const int mg = t >> 5;   // row group (4 rows each), 0..7
    const int kk = t & 31;   // loader: k index
    const int q  = t >> 5;   // loader: row base

    float acc[4][4];
#pragma unroll
    for (int i = 0; i < 4; ++i)
#pragma unroll
        for (int j = 0; j < 4; ++j) acc[i][j] = 0.f;

    for (int k0 = 0; k0 < V_; k0 += KC) {
        // stage A (transposed): 32 m x 32 k
#pragma unroll
        for (int p = 0; p < 4; ++p) {
            int m = q + p * 8;
            As[kk][m] = Vmat[(size_t)(m0 + m) * V_ + k0 + kk];
        }
        // stage W: 128 r x 32 k
#pragma unroll
        for (int p = 0; p < 16; ++p) {
            int r = q + p * 8;
            const float* wrow = (r < 64) ? (U1v + (size_t)r * V_) : (U2v + (size_t)(r - 64) * V_);
            Ws[kk][r] = wrow[k0 + kk];
        }
        __syncthreads();
#pragma unroll
        for (int k = 0; k < KC; ++k) {
            float4 a = *(const float4*)&As[k][mg * 4];
            float4 w = *(const float4*)&Ws[k][ng * 4];
            acc[0][0] += a.x * w.x; acc[0][1] += a.x * w.y; acc[0][2] += a.x * w.z; acc[0][3] += a.x * w.w;
            acc[1][0] += a.y * w.x; acc[1][1] += a.y * w.y; acc[1][2] += a.y * w.z; acc[1][3] += a.y * w.w;
            acc[2][0] += a.z * w.x; acc[2][1] += a.z * w.y; acc[2][2] += a.z * w.z; acc[2][3] += a.z * w.w;
            acc[3][0] += a.w * w.x; acc[3][1] += a.w * w.y; acc[3][2] += a.w * w.z; acc[3][3] += a.w * w.w;
        }
        __syncthreads();
    }
    // epilogue: scale, bias, relu, store float4
    const int rbase = ng * 4;
    float sc[4], bi[4];
#pragma unroll
    for (int j = 0; j < 4; ++j) {
        int r = rbase + j;
        sc[j] = scale[r];
        bi[j] = (r < 64) ? U1b[r] : U2b[r - 64];
    }
#pragma unroll
    for (int i = 0; i < 4; ++i) {
        int m = m0 + mg * 4 + i;
        float4 o;
        o.x = fmaxf(acc[i][0] * sc[0] + bi[0], 0.f);
        o.y = fmaxf(acc[i][1] * sc[1] + bi[1], 0.f);
        o.z = fmaxf(acc[i][2] * sc[2] + bi[2], 0.f);
        o.w = fmaxf(acc[i][3] * sc[3] + bi[3], 0.f);
        *(float4*)&LR[(size_t)m * 128 + rbase] = o;
    }
}

// ---------------- kernel 3: d[bn] = rsqrt(dot(left,right)+1e-6) ----
__global__ void kdiag(const float* __restrict__ LR, float* __restrict__ d) {
    int row = blockIdx.x * 4 + (threadIdx.x >> 6);
    int lane = threadIdx.x & 63;
    const float* p = LR + (size_t)row * 128;
    float v = p[lane] * p[64 + lane];
#pragma unroll
    for (int o = 32; o > 0; o >>= 1) v += __shfl_down(v, o, 64);
    if (lane == 0) d[row] = rsqrtf(v + 1e-6f);
}

// ---------------- kernel 4: Lbar + s (per batch) -------------------
__global__ void kcs(const float* __restrict__ LR, const float* __restrict__ dv,
                    float* __restrict__ s) {
    __shared__ float red[4][64];
    __shared__ float lbar[64];
    const int b = blockIdx.x, t = threadIdx.x;
    const int k = t & 63, g = t >> 6;
    float acc = 0.f;
    for (int n = g; n < N_; n += 4)
        acc += dv[b * N_ + n] * LR[(size_t)(b * N_ + n) * 128 + 64 + k];
    red[g][k] = acc;
    __syncthreads();
    if (t < 64) lbar[t] = red[0][t] + red[1][t] + red[2][t] + red[3][t];
    __syncthreads();
    // phase 2: one thread per m
    const float* rrow = LR + (size_t)(b * N_ + t) * 128;
    float a2 = 0.f;
#pragma unroll 8
    for (int kk = 0; kk < 64; ++kk) a2 += lbar[kk] * rrow[kk];
    s[b * N_ + t] = ((float)(N_ + 1) - dv[b * N_ + t] * a2) * (1.0f / (float)N_);
}

// ---------------- kernel 5: featsT[v][b] = sum_m s[b,m] V[b,m,v] ----
__global__ __launch_bounds__(256) void kfeats(const float* __restrict__ Vmat,
                                              const float* __restrict__ s,
                                              float* __restrict__ featsT) {
    __shared__ float sl[N_];
    const int b = blockIdx.x >> 2, c = blockIdx.x & 3;
    const int t = threadIdx.x;
    sl[t] = s[b * N_ + t];
    __syncthreads();
    const int v = c * 512 + t * 2;
    const float* base = Vmat + (size_t)b * N_ * V_ + v;
    float a0 = 0.f, a1 = 0.f;
    for (int m = 0; m < N_; m += 4) {
        float2 x0 = *(const float2*)(base + (size_t)(m + 0) * V_);
        float2 x1 = *(const float2*)(base + (size_t)(m + 1) * V_);
        float2 x2 = *(const float2*)(base + (size_t)(m + 2) * V_);
        float2 x3 = *(const float2*)(base + (size_t)(m + 3) * V_);
        a0 += sl[m] * x0.x + sl[m + 1] * x1.x + sl[m + 2] * x2.x + sl[m + 3] * x3.x;
        a1 += sl[m] * x0.y + sl[m + 1] * x1.y + sl[m + 2] * x2.y + sl[m + 3] * x3.y;
    }
    featsT[(size_t)v * 64 + b]       = a0;
    featsT[(size_t)(v + 1) * 64 + b] = a1;
}

// ---------------- kernel 6: xT[e][b] = dot(featsT[:,b], W_lin[e,:]) -
// (b_lin dropped: constant per-column shift cancels in BatchNorm)
__global__ __launch_bounds__(256) void klin(const float* __restrict__ featsT,
                                            const float* __restrict__ Wl,
                                            float* __restrict__ xT) {
    const int w = threadIdx.x >> 6, b = threadIdx.x & 63;
    const int e0 = blockIdx.x * 16 + w * 4;
    const float* w0 = Wl + (size_t)(e0 + 0) * V_;
    const float* w1 = Wl + (size_t)(e0 + 1) * V_;
    const float* w2 = Wl + (size_t)(e0 + 2) * V_;
    const float* w3 = Wl + (size_t)(e0 + 3) * V_;
    float a0 = 0.f, a1 = 0.f, a2 = 0.f, a3 = 0.f;
    for (int k = 0; k < V_; k += 4) {
#pragma unroll
        for (int u = 0; u < 4; ++u) {
            float f = featsT[(size_t)(k + u) * 64 + b];
            a0 += f * w0[k + u];
            a1 += f * w1[k + u];
            a2 += f * w2[k + u];
            a3 += f * w3[k + u];
        }
    }
    xT[(size_t)(e0 + 0) * 64 + b] = a0;
    xT[(size_t)(e0 + 1) * 64 + b] = a1;
    xT[(size_t)(e0 + 2) * 64 + b] = a2;
    xT[(size_t)(e0 + 3) * 64 + b] = a3;
}

// ---------------- kernel 7: BatchNorm over batch ------------------
__global__ void kbn(const float* __restrict__ xT, const float* __restrict__ gamma,
                    const float* __restrict__ beta, float* __restrict__ out) {
    __shared__ float xl[4][64];
    const int w = threadIdx.x >> 6, b = threadIdx.x & 63;
    const int e0 = blockIdx.x * 4;
    const int e = e0 + w;
    float v = xT[(size_t)e * 64 + b];
    float sum = v;
#pragma unroll
    for (int o = 1; o < 64; o <<= 1) sum += __shfl_xor(sum, o, 64);
    float mu = sum * (1.f / 64.f);
    float dvv = v - mu;
    float q = dvv * dvv;
#pragma unroll
    for (int o = 1; o < 64; o <<= 1) q += __shfl_xor(q, o, 64);
    float inv = rsqrtf(q * (1.f / 64.f) + 1e-5f);
    xl[w][b] = gamma[e] * dvv * inv + beta[e];
    __syncthreads();
    const int b2 = threadIdx.x >> 2, j = threadIdx.x & 3;
    out[(size_t)b2 * E_ + e0 + j] = xl[j][b2];
}

extern "C" void kernel_launch(void* const* d_in, const int* in_sizes, int n_in,
                              void* d_out, int out_size, void* d_ws, size_t ws_size,
                              hipStream_t stream) {
    const float* Vmat = (const float*)d_in[0];
    const float* U1v  = (const float*)d_in[1];
    const float* U1g  = (const float*)d_in[2];
    const float* U1b  = (const float*)d_in[3];
    const float* U2v  = (const float*)d_in[4];
    const float* U2g  = (const float*)d_in[5];
    const float* U2b  = (const float*)d_in[6];
    const float* Wl   = (const float*)d_in[7];
    // d_in[8] = b_lin: unused (cancels in BatchNorm)
    const float* gam  = (const float*)d_in[9];
    const float* bet  = (const float*)d_in[10];

    float* ws     = (float*)d_ws;
    float* scale  = ws + OFF_SCALE;
    float* dv     = ws + OFF_D;
    float* s      = ws + OFF_S;
    float* LR     = ws + OFF_LR;
    float* featsT = ws + OFF_FT;
    float* xT     = ws + OFF_XT;

    knorm  <<<128, 256, 0, stream>>>(U1v, U1g, U2v, U2g, scale);
    gemm_lr<<<MROWS / 32, 256, 0, stream>>>(Vmat, U1v, U2v, scale, U1b, U2b, LR);
    kdiag  <<<MROWS / 4, 256, 0, stream>>>(LR, dv);
    kcs    <<<B_, 256, 0, stream>>>(LR, dv, s);
    kfeats <<<B_ * 4, 256, 0, stream>>>(Vmat, s, featsT);
    klin   <<<E_ / 16, 256, 0, stream>>>(featsT, Wl, xT);
    kbn    <<<E_ / 4, 256, 0, stream>>>(xT, gam, bet, (float*)d_out);
}

// Round 2
// 347.246 us; speedup vs baseline: 1.3702x; 1.3702x over previous
//
#include <hip/hip_runtime.h>

#define B_ 64
#define N_ 256
#define V_ 2048
#define E_ 1024
#define MROWS 16384  // B_*N_

typedef __bf16 bf16_t;
typedef bf16_t bf16x8 __attribute__((ext_vector_type(8)));
typedef bf16_t bf16x4 __attribute__((ext_vector_type(4)));
typedef float f32x4 __attribute__((ext_vector_type(4)));

// ws layout (float units):
#define OFF_D   0
#define OFF_S   16384
#define OFF_LR  32768
#define OFF_FT  2129920
#define OFF_XT  2260992
#define OFF_WB  2326528   // bf16[128*2048] = 131072 floats worth

// ---------------- kernel 1: weight-norm scale folded into bf16 weights ----
__global__ void kprep(const float* __restrict__ U1v, const float* __restrict__ U1g,
                      const float* __restrict__ U2v, const float* __restrict__ U2g,
                      bf16_t* __restrict__ Wb) {
    __shared__ float red[256];
    __shared__ float sc;
    const int r = blockIdx.x;  // 0..127
    const float* v = (r < 64) ? (U1v + (size_t)r * V_) : (U2v + (size_t)(r - 64) * V_);
    float ss = 0.f;
    for (int i = threadIdx.x; i < V_; i += 256) { float x = v[i]; ss += x * x; }
    red[threadIdx.x] = ss;
    __syncthreads();
    for (int o = 128; o > 0; o >>= 1) {
        if (threadIdx.x < (unsigned)o) red[threadIdx.x] += red[threadIdx.x + o];
        __syncthreads();
    }
    if (threadIdx.x == 0) {
        float g = (r < 64) ? U1g[r] : U2g[r - 64];
        sc = g * rsqrtf(red[0]);
    }
    __syncthreads();
    const float s = sc;
    const int k = threadIdx.x * 8;
    float4 f0 = *(const float4*)(v + k);
    float4 f1 = *(const float4*)(v + k + 4);
    bf16_t* o = Wb + (size_t)r * V_ + k;
    o[0] = (bf16_t)(f0.x * s); o[1] = (bf16_t)(f0.y * s);
    o[2] = (bf16_t)(f0.z * s); o[3] = (bf16_t)(f0.w * s);
    o[4] = (bf16_t)(f1.x * s); o[5] = (bf16_t)(f1.y * s);
    o[6] = (bf16_t)(f1.z * s); o[7] = (bf16_t)(f1.w * s);
}

// ---------------- kernel 2: MFMA bf16 projections -------------------------
// LR[16384 x 128] = relu(Vmat[16384x2048] (bf16) * Wb[128x2048]^T + bias)
// tile 64m x 128n, 256 threads = 4 waves, wave = 32m x 64n (2x4 frags 16x16x32)
#define LDA 40  // bf16 row stride: 80B = 20 banks; 2-way aliasing only (free)
__global__ __launch_bounds__(256) void gemm_lr(
    const float* __restrict__ V, const bf16_t* __restrict__ Wb,
    const float* __restrict__ U1b, const float* __restrict__ U2b,
    float* __restrict__ LR) {
    __shared__ bf16_t As[64 * LDA];
    __shared__ bf16_t Bs[128 * LDA];
    const int t = threadIdx.x;
    const int m0 = blockIdx.x * 64;
    const int w = t >> 6, lane = t & 63;
    const int m0w = (w & 1) * 32, n0w = (w >> 1) * 64;
    const int lm = lane & 15, lq = lane >> 4;
    // staging: A = 64 rows x 32 k fp32 (2 float4/thread), B = 128 rows x 32 k bf16
    const int ar = t >> 2, ac = t & 3;
    const int br = t >> 1, bh = t & 1;
    const float*  aptr = V  + (size_t)(m0 + ar) * V_ + ac * 4;
    const bf16_t* bptr = Wb + (size_t)br * V_ + bh * 16;

    f32x4 acc[2][4];
#pragma unroll
    for (int i = 0; i < 2; ++i)
#pragma unroll
        for (int j = 0; j < 4; ++j) acc[i][j] = (f32x4){0.f, 0.f, 0.f, 0.f};

    float4 ap0 = *(const float4*)(aptr);
    float4 ap1 = *(const float4*)(aptr + 16);
    uint4  bp0 = *(const uint4*)(bptr);
    uint4  bp1 = *(const uint4*)(bptr + 8);

    for (int k0 = 0; k0 < V_; k0 += 32) {
        bf16x4 p0, p1;
        p0.x = (bf16_t)ap0.x; p0.y = (bf16_t)ap0.y; p0.z = (bf16_t)ap0.z; p0.w = (bf16_t)ap0.w;
        p1.x = (bf16_t)ap1.x; p1.y = (bf16_t)ap1.y; p1.z = (bf16_t)ap1.z; p1.w = (bf16_t)ap1.w;
        *(bf16x4*)&As[ar * LDA + ac * 4]      = p0;
        *(bf16x4*)&As[ar * LDA + 16 + ac * 4] = p1;
        *(uint4*)&Bs[br * LDA + bh * 16]     = bp0;
        *(uint4*)&Bs[br * LDA + bh * 16 + 8] = bp1;
        __syncthreads();
        if (k0 + 32 < V_) {  // prefetch next K-tile into registers
            ap0 = *(const float4*)(aptr + k0 + 32);
            ap1 = *(const float4*)(aptr + k0 + 48);
            bp0 = *(const uint4*)(bptr + k0 + 32);
            bp1 = *(const uint4*)(bptr + k0 + 40);
        }
        bf16x8 af[2], bf[4];
        af[0] = *(bf16x8*)&As[(m0w + lm) * LDA + lq * 8];
        af[1] = *(bf16x8*)&As[(m0w + 16 + lm) * LDA + lq * 8];
#pragma unroll
        for (int j = 0; j < 4; ++j)
            bf[j] = *(bf16x8*)&Bs[(n0w + j * 16 + lm) * LDA + lq * 8];
#pragma unroll
        for (int i = 0; i < 2; ++i)
#pragma unroll
            for (int j = 0; j < 4; ++j)
                acc[i][j] = __builtin_amdgcn_mfma_f32_16x16x32_bf16(af[i], bf[j], acc[i][j], 0, 0, 0);
        __syncthreads();
    }
    // epilogue: bias + relu. C/D layout: n = lane&15 (+16j), m = (lane>>4)*4 + reg
#pragma unroll
    for (int j = 0; j < 4; ++j) {
        const int n = n0w + j * 16 + lm;
        const float bi = (n < 64) ? U1b[n] : U2b[n - 64];
#pragma unroll
        for (int i = 0; i < 2; ++i) {
#pragma unroll
            for (int r = 0; r < 4; ++r) {
                const int m = m0 + m0w + i * 16 + lq * 4 + r;
                LR[(size_t)m * 128 + n] = fmaxf(acc[i][j][r] + bi, 0.f);
            }
        }
    }
}

// ---------------- kernel 3: d[bn] = rsqrt(dot(left,right)+1e-6) ----
__global__ void kdiag(const float* __restrict__ LR, float* __restrict__ d) {
    int row = blockIdx.x * 4 + (threadIdx.x >> 6);
    int lane = threadIdx.x & 63;
    const float* p = LR + (size_t)row * 128;
    float v = p[lane] * p[64 + lane];
#pragma unroll
    for (int o = 32; o > 0; o >>= 1) v += __shfl_down(v, o, 64);
    if (lane == 0) d[row] = rsqrtf(v + 1e-6f);
}

// ---------------- kernel 4: Lbar + s (per batch) -------------------
__global__ void kcs(const float* __restrict__ LR, const float* __restrict__ dv,
                    float* __restrict__ s) {
    __shared__ float red[4][64];
    __shared__ float lbar[64];
    const int b = blockIdx.x, t = threadIdx.x;
    const int k = t & 63, g = t >> 6;
    float acc = 0.f;
    for (int n = g; n < N_; n += 4)
        acc += dv[b * N_ + n] * LR[(size_t)(b * N_ + n) * 128 + 64 + k];
    red[g][k] = acc;
    __syncthreads();
    if (t < 64) lbar[t] = red[0][t] + red[1][t] + red[2][t] + red[3][t];
    __syncthreads();
    const float* rrow = LR + (size_t)(b * N_ + t) * 128;
    float a2 = 0.f;
#pragma unroll 8
    for (int kk = 0; kk < 64; ++kk) a2 += lbar[kk] * rrow[kk];
    s[b * N_ + t] = ((float)(N_ + 1) - dv[b * N_ + t] * a2) * (1.0f / (float)N_);
}

// ---------------- kernel 5: featsT[v][b] += partial over m-chunk ----
// grid 512: b(6b) x vc(1b) x mc(2b); atomics into zeroed featsT
__global__ __launch_bounds__(256) void kfeats(const float* __restrict__ Vmat,
                                              const float* __restrict__ s,
                                              float* __restrict__ featsT) {
    const int b = blockIdx.x >> 3, vc = (blockIdx.x >> 2) & 1, mc = blockIdx.x & 3;
    __shared__ float sl[64];
    const int t = threadIdx.x;
    if (t < 64) sl[t] = s[b * N_ + mc * 64 + t];
    __syncthreads();
    const int v = vc * 1024 + t * 4;
    const float* base = Vmat + (size_t)b * N_ * V_ + (size_t)mc * 64 * V_ + v;
    float4 a = {0.f, 0.f, 0.f, 0.f};
    for (int m = 0; m < 64; m += 2) {
        float4 x0 = *(const float4*)(base + (size_t)m * V_);
        float4 x1 = *(const float4*)(base + (size_t)(m + 1) * V_);
        float s0 = sl[m], s1 = sl[m + 1];
        a.x += s0 * x0.x + s1 * x1.x;
        a.y += s0 * x0.y + s1 * x1.y;
        a.z += s0 * x0.z + s1 * x1.z;
        a.w += s0 * x0.w + s1 * x1.w;
    }
    atomicAdd(&featsT[(size_t)(v + 0) * 64 + b], a.x);
    atomicAdd(&featsT[(size_t)(v + 1) * 64 + b], a.y);
    atomicAdd(&featsT[(size_t)(v + 2) * 64 + b], a.z);
    atomicAdd(&featsT[(size_t)(v + 3) * 64 + b], a.w);
}

// ---------------- kernel 6: xT[e][b] = dot(featsT[:,b], W_lin[e,:]) -
// 256 blocks, 4 e-rows each, in-block split-K x4 (b_lin cancels in BN)
__global__ __launch_bounds__(256) void klin(const float* __restrict__ featsT,
                                            const float* __restrict__ Wl,
                                            float* __restrict__ xT) {
    __shared__ float red[4][4][64];
    const int e0 = blockIdx.x * 4;
    const int t = threadIdx.x, b = t & 63, g = t >> 6;
    const float* w0 = Wl + (size_t)(e0 + 0) * V_ + g * 512;
    const float* w1 = Wl + (size_t)(e0 + 1) * V_ + g * 512;
    const float* w2 = Wl + (size_t)(e0 + 2) * V_ + g * 512;
    const float* w3 = Wl + (size_t)(e0 + 3) * V_ + g * 512;
    const float* f = featsT + (size_t)g * 512 * 64 + b;
    float a0 = 0.f, a1 = 0.f, a2 = 0.f, a3 = 0.f;
#pragma unroll 4
    for (int k = 0; k < 512; ++k) {
        float fv = f[(size_t)k * 64];
        a0 += fv * w0[k]; a1 += fv * w1[k]; a2 += fv * w2[k]; a3 += fv * w3[k];
    }
    red[g][0][b] = a0; red[g][1][b] = a1; red[g][2][b] = a2; red[g][3][b] = a3;
    __syncthreads();
    const int e = t >> 6;
    xT[(size_t)(e0 + e) * 64 + b] = red[0][e][b] + red[1][e][b] + red[2][e][b] + red[3][e][b];
}

// ---------------- kernel 7: BatchNorm over batch ------------------
__global__ void kbn(const float* __restrict__ xT, const float* __restrict__ gamma,
                    const float* __restrict__ beta, float* __restrict__ out) {
    __shared__ float xl[4][64];
    const int w = threadIdx.x >> 6, b = threadIdx.x & 63;
    const int e0 = blockIdx.x * 4;
    const int e = e0 + w;
    float v = xT[(size_t)e * 64 + b];
    float sum = v;
#pragma unroll
    for (int o = 1; o < 64; o <<= 1) sum += __shfl_xor(sum, o, 64);
    float mu = sum * (1.f / 64.f);
    float dvv = v - mu;
    float q = dvv * dvv;
#pragma unroll
    for (int o = 1; o < 64; o <<= 1) q += __shfl_xor(q, o, 64);
    float inv = rsqrtf(q * (1.f / 64.f) + 1e-5f);
    xl[w][b] = gamma[e] * dvv * inv + beta[e];
    __syncthreads();
    const int b2 = threadIdx.x >> 2, j = threadIdx.x & 3;
    out[(size_t)b2 * E_ + e0 + j] = xl[j][b2];
}

extern "C" void kernel_launch(void* const* d_in, const int* in_sizes, int n_in,
                              void* d_out, int out_size, void* d_ws, size_t ws_size,
                              hipStream_t stream) {
    const float* Vmat = (const float*)d_in[0];
    const float* U1v  = (const float*)d_in[1];
    const float* U1g  = (const float*)d_in[2];
    const float* U1b  = (const float*)d_in[3];
    const float* U2v  = (const float*)d_in[4];
    const float* U2g  = (const float*)d_in[5];
    const float* U2b  = (const float*)d_in[6];
    const float* Wl   = (const float*)d_in[7];
    // d_in[8] = b_lin: unused (cancels in BatchNorm)
    const float* gam  = (const float*)d_in[9];
    const float* bet  = (const float*)d_in[10];

    float*  ws     = (float*)d_ws;
    float*  dv     = ws + OFF_D;
    float*  s      = ws + OFF_S;
    float*  LR     = ws + OFF_LR;
    float*  featsT = ws + OFF_FT;
    float*  xT     = ws + OFF_XT;
    bf16_t* Wb     = (bf16_t*)(ws + OFF_WB);

    hipMemsetAsync(featsT, 0, (size_t)V_ * B_ * sizeof(float), stream);
    kprep  <<<128, 256, 0, stream>>>(U1v, U1g, U2v, U2g, Wb);
    gemm_lr<<<MROWS / 64, 256, 0, stream>>>(Vmat, Wb, U1b, U2b, LR);
    kdiag  <<<MROWS / 4, 256, 0, stream>>>(LR, dv);
    kcs    <<<B_, 256, 0, stream>>>(LR, dv, s);
    kfeats <<<B_ * 8, 256, 0, stream>>>(Vmat, s, featsT);
    klin   <<<E_ / 4, 256, 0, stream>>>(featsT, Wl, xT);
    kbn    <<<E_ / 4, 256, 0, stream>>>(xT, gam, bet, (float*)d_out);
}

// Round 3
// 323.591 us; speedup vs baseline: 1.4704x; 1.0731x over previous
//
#include <hip/hip_runtime.h>

#define B_ 64
#define N_ 256
#define V_ 2048
#define E_ 1024
#define MROWS 16384  // B_*N_

typedef __bf16 bf16_t;
typedef bf16_t bf16x8 __attribute__((ext_vector_type(8)));
typedef float f32x4 __attribute__((ext_vector_type(4)));

// ws layout (float units):
#define OFF_S   0         // s      [16384]
#define OFF_LR  16384     // LR     [16384*128]
#define OFF_FT  2113536   // featsT [2048*64]
#define OFF_WB  2244608   // Wb bf16[128*2048] (= 131072 floats)

__device__ __forceinline__ void gload_lds16(const bf16_t* g, bf16_t* l) {
    __builtin_amdgcn_global_load_lds((const __attribute__((address_space(1))) void*)g,
                                     (__attribute__((address_space(3))) void*)l, 16, 0, 0);
}

// ---------------- kernel 1: weight-norm scale folded into bf16 weights ----
__global__ void kprep(const float* __restrict__ U1v, const float* __restrict__ U1g,
                      const float* __restrict__ U2v, const float* __restrict__ U2g,
                      bf16_t* __restrict__ Wb) {
    __shared__ float red[256];
    __shared__ float sc;
    const int r = blockIdx.x;  // 0..127
    const float* v = (r < 64) ? (U1v + (size_t)r * V_) : (U2v + (size_t)(r - 64) * V_);
    float ss = 0.f;
    for (int i = threadIdx.x; i < V_; i += 256) { float x = v[i]; ss += x * x; }
    red[threadIdx.x] = ss;
    __syncthreads();
    for (int o = 128; o > 0; o >>= 1) {
        if (threadIdx.x < (unsigned)o) red[threadIdx.x] += red[threadIdx.x + o];
        __syncthreads();
    }
    if (threadIdx.x == 0) {
        float g = (r < 64) ? U1g[r] : U2g[r - 64];
        sc = g * rsqrtf(red[0]);
    }
    __syncthreads();
    const float s = sc;
    const int k = threadIdx.x * 8;
    float4 f0 = *(const float4*)(v + k);
    float4 f1 = *(const float4*)(v + k + 4);
    bf16x8 o;
    o[0] = (bf16_t)(f0.x * s); o[1] = (bf16_t)(f0.y * s);
    o[2] = (bf16_t)(f0.z * s); o[3] = (bf16_t)(f0.w * s);
    o[4] = (bf16_t)(f1.x * s); o[5] = (bf16_t)(f1.y * s);
    o[6] = (bf16_t)(f1.z * s); o[7] = (bf16_t)(f1.w * s);
    *(bf16x8*)(Wb + (size_t)r * V_ + k) = o;
}

// ---------------- kernel 2: MFMA bf16 projections -------------------------
// LR[16384x128] = relu(Vmat * Wb^T + bias). Tile 32m x 128n, BK=64, grid 512.
// 4 waves: wave w covers n in [w*32, w*32+32). XOR-swizzled LDS (16B chunks),
// B staged via global_load_lds dwordx4, A converted fp32->bf16 in regs.
#define BK 64
__global__ __launch_bounds__(256) void gemm_lr(
    const float* __restrict__ V, const bf16_t* __restrict__ Wb,
    const float* __restrict__ U1b, const float* __restrict__ U2b,
    float* __restrict__ LR) {
    __shared__ bf16_t As[32 * BK];    // row stride 128B, swizzled
    __shared__ bf16_t Bs[128 * BK];
    const int t = threadIdx.x;
    const int m0 = blockIdx.x * 32;
    const int wv = t >> 6, lane = t & 63;
    const int lm = lane & 15, lq = lane >> 4;
    const int n0w = wv * 32;

    // A staging: thread -> (row 0..31, 8-elem chunk u 0..7)
    const int arow = t >> 3, au = t & 7;
    const float* aptr = V + (size_t)(m0 + arow) * V_ + au * 8;
    bf16_t* adst = &As[arow * BK + ((au ^ (arow & 7)) * 8)];

    // B DMA: lane -> (row = q*32 + wv*8 + rloc, swizzled chunk uu)
    const int rloc = lane >> 3;
    const int uu = (lane & 7) ^ rloc;
    const bf16_t* bgbase = Wb + (size_t)(wv * 8 + rloc) * V_ + uu * 8;

    f32x4 acc[2][2];
#pragma unroll
    for (int i = 0; i < 2; ++i)
#pragma unroll
        for (int j = 0; j < 2; ++j) acc[i][j] = (f32x4){0.f, 0.f, 0.f, 0.f};

    // prologue: B DMA for k0=0, A regs for k0=0
#pragma unroll
    for (int q = 0; q < 4; ++q)
        gload_lds16(bgbase + (size_t)q * 32 * V_, &Bs[(q * 32 + wv * 8) * BK]);
    float4 ap0 = *(const float4*)(aptr);
    float4 ap1 = *(const float4*)(aptr + 4);

    for (int k0 = 0; k0 < V_; k0 += BK) {
        // convert + write A for this iter
        bf16x8 av;
        av[0] = (bf16_t)ap0.x; av[1] = (bf16_t)ap0.y; av[2] = (bf16_t)ap0.z; av[3] = (bf16_t)ap0.w;
        av[4] = (bf16_t)ap1.x; av[5] = (bf16_t)ap1.y; av[6] = (bf16_t)ap1.z; av[7] = (bf16_t)ap1.w;
        *(bf16x8*)adst = av;
        __syncthreads();  // B DMA + A writes visible

        bf16x8 af[2][2], bfr[2][2];
#pragma unroll
        for (int i = 0; i < 2; ++i)
#pragma unroll
            for (int kf = 0; kf < 2; ++kf)
                af[i][kf] = *(bf16x8*)&As[(i * 16 + lm) * BK + (((kf * 4 + lq) ^ (lm & 7)) * 8)];
#pragma unroll
        for (int j = 0; j < 2; ++j)
#pragma unroll
            for (int kf = 0; kf < 2; ++kf)
                bfr[j][kf] = *(bf16x8*)&Bs[(n0w + j * 16 + lm) * BK + (((kf * 4 + lq) ^ (lm & 7)) * 8)];

        if (k0 + BK < V_) {  // A reg prefetch for next iter
            ap0 = *(const float4*)(aptr + k0 + BK);
            ap1 = *(const float4*)(aptr + k0 + BK + 4);
        }
#pragma unroll
        for (int i = 0; i < 2; ++i)
#pragma unroll
            for (int j = 0; j < 2; ++j) {
                acc[i][j] = __builtin_amdgcn_mfma_f32_16x16x32_bf16(af[i][0], bfr[j][0], acc[i][j], 0, 0, 0);
                acc[i][j] = __builtin_amdgcn_mfma_f32_16x16x32_bf16(af[i][1], bfr[j][1], acc[i][j], 0, 0, 0);
            }
        __syncthreads();  // done reading As/Bs
        if (k0 + BK < V_) {
#pragma unroll
            for (int q = 0; q < 4; ++q)
                gload_lds16(bgbase + (size_t)q * 32 * V_ + (k0 + BK), &Bs[(q * 32 + wv * 8) * BK]);
        }
    }
    // epilogue: bias + relu. C/D: n = lane&15 (+16j), m = lq*4 + reg (+16i)
#pragma unroll
    for (int j = 0; j < 2; ++j) {
        const int n = n0w + j * 16 + lm;
        const float bi = (n < 64) ? U1b[n] : U2b[n - 64];
#pragma unroll
        for (int i = 0; i < 2; ++i)
#pragma unroll
            for (int r = 0; r < 4; ++r) {
                const int m = m0 + i * 16 + lq * 4 + r;
                LR[(size_t)m * 128 + n] = fmaxf(acc[i][j][r] + bi, 0.f);
            }
    }
}

// ---------------- kernel 3: fused d + Lbar + s (per batch) ----------------
__global__ __launch_bounds__(256) void kds(const float* __restrict__ LR, float* __restrict__ s) {
    __shared__ float dl[256];
    __shared__ float red[4][64];
    __shared__ float lbar[64];
    const int b = blockIdx.x, t = threadIdx.x;
    const float* Lb = LR + (size_t)b * N_ * 128;
    const float* row = Lb + (size_t)t * 128;
    // phase 0: d[t] = rsqrt(dot(right,left)+1e-6)
    float dd = 0.f;
#pragma unroll
    for (int k = 0; k < 64; k += 4) {
        float4 l = *(const float4*)(row + k);
        float4 r = *(const float4*)(row + 64 + k);
        dd += l.x * r.x + l.y * r.y + l.z * r.z + l.w * r.w;
    }
    const float dv = rsqrtf(dd + 1e-6f);
    dl[t] = dv;
    __syncthreads();
    // phase 1: lbar[k] = sum_n dl[n] * left[n][k]
    const int k = t & 63, g = t >> 6;
    float acc = 0.f;
    for (int n = g; n < N_; n += 4)
        acc += dl[n] * Lb[(size_t)n * 128 + 64 + k];
    red[g][k] = acc;
    __syncthreads();
    if (t < 64) lbar[t] = red[0][t] + red[1][t] + red[2][t] + red[3][t];
    __syncthreads();
    // phase 2: s[t]
    float a2 = 0.f;
#pragma unroll 8
    for (int kk = 0; kk < 64; ++kk) a2 += lbar[kk] * row[kk];
    s[b * N_ + t] = ((float)(N_ + 1) - dv * a2) * (1.0f / (float)N_);
}

// ---------------- kernel 4: featsT[v][b] += partial over m-chunk ----------
__global__ __launch_bounds__(256) void kfeats(const float* __restrict__ Vmat,
                                              const float* __restrict__ s,
                                              float* __restrict__ featsT) {
    const int b = blockIdx.x >> 3, vc = (blockIdx.x >> 2) & 1, mc = blockIdx.x & 3;
    __shared__ float sl[64];
    const int t = threadIdx.x;
    if (t < 64) sl[t] = s[b * N_ + mc * 64 + t];
    __syncthreads();
    const int v = vc * 1024 + t * 4;
    const float* base = Vmat + (size_t)b * N_ * V_ + (size_t)mc * 64 * V_ + v;
    float4 a = {0.f, 0.f, 0.f, 0.f};
    for (int m = 0; m < 64; m += 8) {
        float4 x[8];
#pragma unroll
        for (int u = 0; u < 8; ++u) x[u] = *(const float4*)(base + (size_t)(m + u) * V_);
#pragma unroll
        for (int u = 0; u < 8; ++u) {
            float sv = sl[m + u];
            a.x += sv * x[u].x; a.y += sv * x[u].y;
            a.z += sv * x[u].z; a.w += sv * x[u].w;
        }
    }
    atomicAdd(&featsT[(size_t)(v + 0) * 64 + b], a.x);
    atomicAdd(&featsT[(size_t)(v + 1) * 64 + b], a.y);
    atomicAdd(&featsT[(size_t)(v + 2) * 64 + b], a.z);
    atomicAdd(&featsT[(size_t)(v + 3) * 64 + b], a.w);
}

// ---------------- kernel 5: fused linear + BatchNorm ----------------------
// block -> 4 e-rows complete across b, so BN is a wave-level shuffle.
// (b_lin dropped: constant per-column shift cancels in BatchNorm)
__global__ __launch_bounds__(256) void klinbn(const float* __restrict__ featsT,
                                              const float* __restrict__ Wl,
                                              const float* __restrict__ gamma,
                                              const float* __restrict__ beta,
                                              float* __restrict__ out) {
    __shared__ float red[4][4][64];
    const int e0 = blockIdx.x * 4;
    const int t = threadIdx.x, b = t & 63, g = t >> 6;
    const float* w0 = Wl + (size_t)(e0 + 0) * V_ + g * 512;
    const float* w1 = Wl + (size_t)(e0 + 1) * V_ + g * 512;
    const float* w2 = Wl + (size_t)(e0 + 2) * V_ + g * 512;
    const float* w3 = Wl + (size_t)(e0 + 3) * V_ + g * 512;
    const float* f = featsT + (size_t)g * 512 * 64 + b;
    float a0 = 0.f, a1 = 0.f, a2 = 0.f, a3 = 0.f;
#pragma unroll 4
    for (int k = 0; k < 512; ++k) {
        float fv = f[(size_t)k * 64];
        a0 += fv * w0[k]; a1 += fv * w1[k]; a2 += fv * w2[k]; a3 += fv * w3[k];
    }
    red[g][0][b] = a0; red[g][1][b] = a1; red[g][2][b] = a2; red[g][3][b] = a3;
    __syncthreads();
    const int e = t >> 6;  // wave e owns e-row e0+e across lanes b
    float v = red[0][e][b] + red[1][e][b] + red[2][e][b] + red[3][e][b];
    float sum = v;
#pragma unroll
    for (int o = 1; o < 64; o <<= 1) sum += __shfl_xor(sum, o, 64);
    float mu = sum * (1.f / 64.f);
    float dvv = v - mu;
    float q = dvv * dvv;
#pragma unroll
    for (int o = 1; o < 64; o <<= 1) q += __shfl_xor(q, o, 64);
    float inv = rsqrtf(q * (1.f / 64.f) + 1e-5f);
    float res = gamma[e0 + e] * dvv * inv + beta[e0 + e];
    __syncthreads();
    red[0][e][b] = res;
    __syncthreads();
    const int b2 = t >> 2, j = t & 3;
    out[(size_t)b2 * E_ + e0 + j] = red[0][j][b2];
}

extern "C" void kernel_launch(void* const* d_in, const int* in_sizes, int n_in,
                              void* d_out, int out_size, void* d_ws, size_t ws_size,
                              hipStream_t stream) {
    const float* Vmat = (const float*)d_in[0];
    const float* U1v  = (const float*)d_in[1];
    const float* U1g  = (const float*)d_in[2];
    const float* U1b  = (const float*)d_in[3];
    const float* U2v  = (const float*)d_in[4];
    const float* U2g  = (const float*)d_in[5];
    const float* U2b  = (const float*)d_in[6];
    const float* Wl   = (const float*)d_in[7];
    // d_in[8] = b_lin: unused (cancels in BatchNorm)
    const float* gam  = (const float*)d_in[9];
    const float* bet  = (const float*)d_in[10];

    float*  ws     = (float*)d_ws;
    float*  s      = ws + OFF_S;
    float*  LR     = ws + OFF_LR;
    float*  featsT = ws + OFF_FT;
    bf16_t* Wb     = (bf16_t*)(ws + OFF_WB);

    hipMemsetAsync(featsT, 0, (size_t)V_ * B_ * sizeof(float), stream);
    kprep  <<<128, 256, 0, stream>>>(U1v, U1g, U2v, U2g, Wb);
    gemm_lr<<<MROWS / 32, 256, 0, stream>>>(Vmat, Wb, U1b, U2b, LR);
    kds    <<<B_, 256, 0, stream>>>(LR, s);
    kfeats <<<B_ * 8, 256, 0, stream>>>(Vmat, s, featsT);
    klinbn <<<E_ / 4, 256, 0, stream>>>(featsT, Wl, gam, bet, (float*)d_out);
}